// Round 3
// baseline (301.182 us; speedup 1.0000x reference)
//
#include <hip/hip_runtime.h>

// LearnedSegmentEncoder on MI355X — MFMA + partial-sum (no global atomics).
// B=8, C=128, P=65536, D=64, S=32.
// Identity: pooled = conv2_w @ mean_seg(relu(conv1_w@x+b1)) + b2 (conv2 hoisted
// past the segment mean), so only conv1 runs per-pixel — as a bf16 MFMA GEMM
// with A-fragments loaded straight from global (coalesced, no LDS staging).
// Per-block segment sums stream to a partial buffer; a reduce kernel folds them.

#define B_ 8
#define C_ 128
#define P_ 65536
#define D_ 64
#define S_ 32
#define PB 128            // blocks per batch (pixels/block = 512)

typedef short  bf16x8 __attribute__((ext_vector_type(8)));
typedef float  f32x4  __attribute__((ext_vector_type(4)));

__device__ __forceinline__ short f2bf(float f) {
  union { float f; unsigned u; } v; v.f = f;
  unsigned r = v.u + 0x7fffu + ((v.u >> 16) & 1u);   // RNE
  return (short)(r >> 16);
}

__global__ __launch_bounds__(256) void w1_to_bf16(const float* __restrict__ w1,
                                                  short* __restrict__ wbf) {
  int i = blockIdx.x * 256 + threadIdx.x;
  if (i < C_ * D_) wbf[i] = f2bf(w1[i]);
}

// 256 thr = 4 waves; each wave does 8 pixel-tiles of 16 -> 512 pixels/block.
// Grid (PB, B). PARTIALS: stream per-block sums; else atomic into gsum/gcnt.
template<bool PARTIALS>
__global__ __launch_bounds__(256, 4) void proj_mfma(
    const int* __restrict__ labels, const float* __restrict__ feat,
    const short* __restrict__ wbf, const float* __restrict__ b1,
    float* __restrict__ sum_out, int* __restrict__ cnt_out)
{
  __shared__ float s_acc[S_][68];   // pad 68 spreads labels across banks
  __shared__ int   s_cnt[S_];

  const int tid  = threadIdx.x;
  const int wave = tid >> 6, l = tid & 63, m = l & 15, g = l >> 4;
  const int b     = blockIdx.y;
  const int pbase = blockIdx.x * 512;

  for (int i = tid; i < S_ * 68; i += 256) ((float*)s_acc)[i] = 0.f;
  if (tid < S_) s_cnt[tid] = 0;

  // B-fragments (W1^T as K x N): lane l, tile nt, kstep ks reads
  // w1[d = nt*16+m][c = ks*32 + g*8 + j], j=0..7 — 16B contiguous.
  bf16x8 bfr[4][4];
  #pragma unroll
  for (int nt = 0; nt < 4; ++nt)
    #pragma unroll
    for (int ks = 0; ks < 4; ++ks)
      bfr[nt][ks] = *(const bf16x8*)&wbf[(nt * 16 + m) * C_ + ks * 32 + g * 8];

  float b1v[4];
  #pragma unroll
  for (int nt = 0; nt < 4; ++nt) b1v[nt] = b1[nt * 16 + m];

  __syncthreads();

  const float* xb = feat   + (size_t)b * C_ * P_;
  const int*   lb = labels + (size_t)b * P_;

  #pragma unroll 2
  for (int t = 0; t < 8; ++t) {
    const int p0 = pbase + (wave + 4 * t) * 16;

    // labels for output rows: row = g*4 + r  -> pixel p0 + g*4 + r
    const int4 labv = *(const int4*)&lb[p0 + g * 4];

    // A-fragments direct from global: lane reads x[c = ks*32+g*8+j][p0+m].
    const float* xp = xb + (size_t)(g * 8) * P_ + p0 + m;
    float xv[4][8];
    #pragma unroll
    for (int ks = 0; ks < 4; ++ks)
      #pragma unroll
      for (int j = 0; j < 8; ++j)
        xv[ks][j] = xp[(size_t)(ks * 32 + j) * P_];

    bf16x8 af[4];
    #pragma unroll
    for (int ks = 0; ks < 4; ++ks)
      #pragma unroll
      for (int j = 0; j < 8; ++j)
        af[ks][j] = f2bf(xv[ks][j]);

    f32x4 acc[4] = {{0,0,0,0},{0,0,0,0},{0,0,0,0},{0,0,0,0}};
    #pragma unroll
    for (int nt = 0; nt < 4; ++nt)
      #pragma unroll
      for (int ks = 0; ks < 4; ++ks)
        acc[nt] = __builtin_amdgcn_mfma_f32_16x16x32_bf16(af[ks], bfr[nt][ks],
                                                          acc[nt], 0, 0, 0);

    // C/D layout: d = nt*16 + (lane&15), pixel-row = g*4 + r.
    #pragma unroll
    for (int nt = 0; nt < 4; ++nt) {
      #pragma unroll
      for (int r = 0; r < 4; ++r) {
        const int lab = (r & 2) ? ((r & 1) ? labv.w : labv.z)
                                : ((r & 1) ? labv.y : labv.x);
        const float v = fmaxf(acc[nt][r] + b1v[nt], 0.f);
        atomicAdd(&s_acc[lab & (S_ - 1)][nt * 16 + m], v);
      }
    }
    if (m < 4) {
      const int lab = (m & 2) ? ((m & 1) ? labv.w : labv.z)
                              : ((m & 1) ? labv.y : labv.x);
      atomicAdd(&s_cnt[lab & (S_ - 1)], 1);
    }
  }

  __syncthreads();
  if (PARTIALS) {
    float* myp = sum_out + (size_t)(b * PB + blockIdx.x) * (S_ * D_);
    for (int i = tid; i < S_ * D_; i += 256) myp[i] = s_acc[i >> 6][i & 63];
    if (tid < S_) cnt_out[(b * PB + blockIdx.x) * S_ + tid] = s_cnt[tid];
  } else {
    for (int i = tid; i < S_ * D_; i += 256)
      atomicAdd(&sum_out[((size_t)b * S_ + (i >> 6)) * D_ + (i & 63)],
                s_acc[i >> 6][i & 63]);
    if (tid < S_) atomicAdd(&cnt_out[b * S_ + tid], s_cnt[tid]);
  }
}

// Grid (S, B), 256 threads: fold 128 block-partials into gsum/gcnt.
__global__ __launch_bounds__(256) void reduce_partials(
    const float* __restrict__ psum, const int* __restrict__ pcnt,
    float* __restrict__ gsum, int* __restrict__ gcnt)
{
  const int s = blockIdx.x, b = blockIdx.y;
  const int tid = threadIdx.x, d = tid & 63, c = tid >> 6;
  __shared__ float red[4][D_];
  __shared__ int ctot;
  if (tid == 0) ctot = 0;

  float v = 0.f;
  for (int pb = c; pb < PB; pb += 4)
    v += psum[(size_t)(b * PB + pb) * (S_ * D_) + s * D_ + d];
  red[c][d] = v;
  __syncthreads();
  if (tid < D_)
    gsum[((size_t)b * S_ + s) * D_ + d] = red[0][d] + red[1][d] + red[2][d] + red[3][d];
  if (tid < PB) atomicAdd(&ctot, pcnt[(b * PB + tid) * S_ + s]);
  __syncthreads();
  if (tid == 0) gcnt[b * S_ + s] = ctot;
}

// One block per batch, 64 lanes (one wave, lane o = output channel).
__global__ __launch_bounds__(64) void seg_finalize(
    const float* __restrict__ gsum, const int* __restrict__ gcnt,
    const float* __restrict__ w2, const float* __restrict__ b2,
    const float* __restrict__ emb, const float* __restrict__ wo,
    const float* __restrict__ bo, float* __restrict__ out)
{
  const int b = blockIdx.x, o = threadIdx.x;
  __shared__ float s_mean[D_], s_pool[D_];
  int rank = 0;
  for (int s = 0; s < S_; ++s) {
    const int cnt = gcnt[b * S_ + s];                  // uniform across lanes
    const float inv = 1.f / (float)max(cnt, 1);
    s_mean[o] = gsum[((size_t)b * S_ + s) * D_ + o] * inv;
    __syncthreads();
    float pooled = b2[o];
    #pragma unroll
    for (int d = 0; d < D_; ++d) pooled += w2[o * D_ + d] * s_mean[d];
    s_pool[o] = pooled;
    __syncthreads();
    float r = bo[o];
    #pragma unroll
    for (int e = 0; e < D_; ++e) r += wo[o * 2 * D_ + e] * s_pool[e];
    #pragma unroll
    for (int e = 0; e < D_; ++e) r += wo[o * 2 * D_ + D_ + e] * emb[s * D_ + e];
    if (cnt > 0) {                                     // uniform branch
      out[((size_t)b * S_ + rank) * D_ + o] = r;
      rank++;
    }
    __syncthreads();
  }
}

extern "C" void kernel_launch(void* const* d_in, const int* in_sizes, int n_in,
                              void* d_out, int out_size, void* d_ws, size_t ws_size,
                              hipStream_t stream) {
  const int*   labels = (const int*)  d_in[0];
  const float* feat   = (const float*)d_in[1];
  const float* w1     = (const float*)d_in[2];
  const float* b1     = (const float*)d_in[3];
  const float* w2     = (const float*)d_in[4];
  const float* b2     = (const float*)d_in[5];
  const float* emb    = (const float*)d_in[6];
  const float* wo     = (const float*)d_in[7];
  const float* bo     = (const float*)d_in[8];
  float* out = (float*)d_out;

  // ws layout: gsum | gcnt | wbf | psum | pcnt
  char* w = (char*)d_ws;
  float* gsum = (float*)w;                       w += (size_t)B_ * S_ * D_ * 4;
  int*   gcnt = (int*)w;                         w += (size_t)B_ * S_ * 4;
  short* wbf  = (short*)w;                       w += (size_t)C_ * D_ * 2;
  float* psum = (float*)w;                       w += (size_t)B_ * PB * S_ * D_ * 4;
  int*   pcnt = (int*)w;                         w += (size_t)B_ * PB * S_ * 4;
  const bool use_partials = ((size_t)(w - (char*)d_ws) <= ws_size);

  hipMemsetAsync(d_out, 0, (size_t)out_size * sizeof(float), stream);
  if (!use_partials) {
    hipMemsetAsync(d_ws, 0,
                   (size_t)B_ * S_ * D_ * 4 + (size_t)B_ * S_ * 4, stream);
  }

  w1_to_bf16<<<(C_ * D_ + 255) / 256, 256, 0, stream>>>(w1, wbf);

  dim3 grid(PB, B_);
  if (use_partials) {
    proj_mfma<true><<<grid, 256, 0, stream>>>(labels, feat, wbf, b1, psum, pcnt);
    reduce_partials<<<dim3(S_, B_), 256, 0, stream>>>(psum, pcnt, gsum, gcnt);
  } else {
    proj_mfma<false><<<grid, 256, 0, stream>>>(labels, feat, wbf, b1, gsum, gcnt);
  }
  seg_finalize<<<B_, 64, 0, stream>>>(gsum, gcnt, w2, b2, emb, wo, bo, out);
}

// Round 4
// 233.578 us; speedup vs baseline: 1.2894x; 1.2894x over previous
//
#include <hip/hip_runtime.h>

// LearnedSegmentEncoder on MI355X — global_load_lds + counted-vmcnt pipeline.
// B=8, C=128, P=65536, D=64, S=32.
// Identity: pooled = conv2_w @ mean_seg(relu(conv1_w@x+b1)) + b2 (conv2 hoisted
// past the segment mean), so only conv1 runs per-pixel: bf16 MFMA GEMM.
// Features stream HBM->LDS via fire-and-forget global_load_lds (dwordx4),
// double-buffered with counted vmcnt (never drained to 0 mid-loop).

#define B_ 8
#define C_ 128
#define P_ 65536
#define D_ 64
#define S_ 32
#define TM 256                 // pixels per block
#define KC 32                  // channels per chunk
#define NCH (C_ / KC)          // 4 chunks

typedef short  bf16x8 __attribute__((ext_vector_type(8)));
typedef float  f32x4  __attribute__((ext_vector_type(4)));

__device__ __forceinline__ short f2bf(float f) {
  union { float f; unsigned u; } v; v.f = f;
  unsigned r = v.u + 0x7fffu + ((v.u >> 16) & 1u);   // RNE
  return (short)(r >> 16);
}

__device__ __forceinline__ void gload16(const float* g, float* l) {
  __builtin_amdgcn_global_load_lds(
      (const __attribute__((address_space(1))) void*)g,
      (__attribute__((address_space(3))) void*)l, 16, 0, 0);
}

__global__ __launch_bounds__(256) void w1_to_bf16(const float* __restrict__ w1,
                                                  short* __restrict__ wbf) {
  int i = blockIdx.x * 256 + threadIdx.x;
  if (i < C_ * D_) wbf[i] = f2bf(w1[i]);
}

// Grid (P/TM, B), 256 threads = 4 waves; wave owns 64 px = 4 MFMA row-tiles.
__global__ __launch_bounds__(256, 2) void proj_mfma(
    const int* __restrict__ labels, const float* __restrict__ feat,
    const short* __restrict__ wbf, const float* __restrict__ b1,
    float* __restrict__ gsum, int* __restrict__ gcnt)
{
  __shared__ __align__(16) float lds_x[2][KC * TM];   // 2 x 32 KB
  __shared__ float s_acc[S_][68];
  __shared__ int   s_cnt[S_];

  const int tid  = threadIdx.x;
  const int wave = tid >> 6, l = tid & 63, m = l & 15, g = l >> 4;
  const int b    = blockIdx.y;
  const int px0  = blockIdx.x * TM;

  for (int i = tid; i < S_ * 68; i += 256) ((float*)s_acc)[i] = 0.f;
  if (tid < S_) s_cnt[tid] = 0;
  __syncthreads();                        // before any vmem: drain is free

  const float* xb = feat + (size_t)b * C_ * P_ + px0;
  const int lane4 = l * 4;

  // stage chunk 0: wave stages rows wave*8..wave*8+7 (1 KB each, coalesced)
  #pragma unroll
  for (int i = 0; i < 8; ++i)
    gload16(xb + (size_t)(wave * 8 + i) * P_ + lane4,
            &lds_x[0][(wave * 8 + i) * TM]);

  f32x4 acc[4][4];
  #pragma unroll
  for (int t = 0; t < 4; ++t)
    #pragma unroll
    for (int nt = 0; nt < 4; ++nt) acc[t][nt] = (f32x4){0.f, 0.f, 0.f, 0.f};

  #pragma unroll
  for (int kc = 0; kc < NCH; ++kc) {
    // W1^T B-fragments for this k-chunk (16 KB table, L2-resident):
    // lane reads w1bf[d = nt*16+m][c = kc*32 + g*8 + j] — 16B contiguous.
    bf16x8 bw[4];
    #pragma unroll
    for (int nt = 0; nt < 4; ++nt)
      bw[nt] = *(const bf16x8*)&wbf[(nt * 16 + m) * C_ + kc * KC + g * 8];

    if (kc + 1 < NCH) {
      #pragma unroll
      for (int i = 0; i < 8; ++i)
        gload16(xb + (size_t)((kc + 1) * KC + wave * 8 + i) * P_ + lane4,
                &lds_x[(kc + 1) & 1][(wave * 8 + i) * TM]);
      // outstanding: c_kc(<=8) + bw(4) + c_{kc+1}(8) -> leave the newest 8
      asm volatile("s_waitcnt vmcnt(8)" ::: "memory");
    } else {
      asm volatile("s_waitcnt vmcnt(0)" ::: "memory");
    }
    __builtin_amdgcn_s_barrier();
    asm volatile("" ::: "memory");

    const float* bp = lds_x[kc & 1];
    #pragma unroll
    for (int t = 0; t < 4; ++t) {
      const int bpx = wave * 64 + t * 16 + m;
      bf16x8 af;
      #pragma unroll
      for (int j = 0; j < 8; ++j)
        af[j] = f2bf(bp[(g * 8 + j) * TM + bpx]);
      #pragma unroll
      for (int nt = 0; nt < 4; ++nt)
        acc[t][nt] = __builtin_amdgcn_mfma_f32_16x16x32_bf16(af, bw[nt],
                                                             acc[t][nt], 0, 0, 0);
    }
    // all ds_reads retired before anyone overwrites this buffer
    asm volatile("s_waitcnt lgkmcnt(0)" ::: "memory");
    __builtin_amdgcn_sched_barrier(0);
    __builtin_amdgcn_s_barrier();
  }

  // ---- epilogue: relu + bias, label scatter into LDS, global flush ----
  float b1v[4];
  #pragma unroll
  for (int nt = 0; nt < 4; ++nt) b1v[nt] = b1[nt * 16 + m];

  const int* lb = labels + (size_t)b * P_ + px0;
  #pragma unroll
  for (int t = 0; t < 4; ++t) {
    const int4 lv = *(const int4*)&lb[wave * 64 + t * 16 + g * 4];
    #pragma unroll
    for (int nt = 0; nt < 4; ++nt) {
      #pragma unroll
      for (int r = 0; r < 4; ++r) {
        const int lab = ((r & 2) ? ((r & 1) ? lv.w : lv.z)
                                 : ((r & 1) ? lv.y : lv.x)) & (S_ - 1);
        const float v = fmaxf(acc[t][nt][r] + b1v[nt], 0.f);
        atomicAdd(&s_acc[lab][nt * 16 + m], v);
      }
    }
    if (m < 4) {
      const int lab = ((m & 2) ? ((m & 1) ? lv.w : lv.z)
                               : ((m & 1) ? lv.y : lv.x)) & (S_ - 1);
      atomicAdd(&s_cnt[lab], 1);
    }
  }

  __syncthreads();
  for (int i = tid; i < S_ * D_; i += 256)
    atomicAdd(&gsum[(size_t)b * S_ * D_ + i], s_acc[i >> 6][i & 63]);
  if (tid < S_) atomicAdd(&gcnt[b * S_ + tid], s_cnt[tid]);
}

// Grid (S, B), 64 lanes: all (b,s) blocks independent; ballot-based rank.
__global__ __launch_bounds__(64) void seg_finalize2(
    const float* __restrict__ gsum, const int* __restrict__ gcnt,
    const float* __restrict__ w2, const float* __restrict__ b2,
    const float* __restrict__ emb, const float* __restrict__ wo,
    const float* __restrict__ bo, float* __restrict__ out)
{
  const int s = blockIdx.x, b = blockIdx.y, o = threadIdx.x;
  const int co = (o < S_) ? gcnt[b * S_ + o] : 0;
  const unsigned long long mask = __ballot(co > 0);
  const int cnt = gcnt[b * S_ + s];
  if (cnt <= 0) return;                               // uniform exit
  const int rank = __popcll(mask & ((1ull << s) - 1ull));

  __shared__ float s_mean[D_], s_pool[D_];
  s_mean[o] = gsum[((size_t)b * S_ + s) * D_ + o] * (1.f / (float)cnt);
  __syncthreads();
  float pooled = b2[o];
  #pragma unroll
  for (int d = 0; d < D_; ++d) pooled += w2[o * D_ + d] * s_mean[d];
  s_pool[o] = pooled;
  __syncthreads();
  float r = bo[o];
  #pragma unroll
  for (int e = 0; e < D_; ++e) r += wo[o * 2 * D_ + e] * s_pool[e];
  #pragma unroll
  for (int e = 0; e < D_; ++e) r += wo[o * 2 * D_ + D_ + e] * emb[s * D_ + e];
  out[((size_t)b * S_ + rank) * D_ + o] = r;
}

extern "C" void kernel_launch(void* const* d_in, const int* in_sizes, int n_in,
                              void* d_out, int out_size, void* d_ws, size_t ws_size,
                              hipStream_t stream) {
  const int*   labels = (const int*)  d_in[0];
  const float* feat   = (const float*)d_in[1];
  const float* w1     = (const float*)d_in[2];
  const float* b1     = (const float*)d_in[3];
  const float* w2     = (const float*)d_in[4];
  const float* b2     = (const float*)d_in[5];
  const float* emb    = (const float*)d_in[6];
  const float* wo     = (const float*)d_in[7];
  const float* bo     = (const float*)d_in[8];
  float* out = (float*)d_out;

  // ws layout: gsum | gcnt | wbf
  char* w = (char*)d_ws;
  float* gsum = (float*)w;   w += (size_t)B_ * S_ * D_ * 4;
  int*   gcnt = (int*)w;     w += (size_t)B_ * S_ * 4;
  short* wbf  = (short*)w;

  hipMemsetAsync(d_ws, 0, (size_t)B_ * S_ * D_ * 4 + (size_t)B_ * S_ * 4, stream);
  hipMemsetAsync(d_out, 0, (size_t)out_size * sizeof(float), stream);

  w1_to_bf16<<<(C_ * D_ + 255) / 256, 256, 0, stream>>>(w1, wbf);

  dim3 grid(P_ / TM, B_);
  proj_mfma<<<grid, 256, 0, stream>>>(labels, feat, wbf, b1, gsum, gcnt);
  seg_finalize2<<<dim3(S_, B_), 64, 0, stream>>>(gsum, gcnt, w2, b2, emb, wo, bo, out);
}

// Round 5
// 203.443 us; speedup vs baseline: 1.4804x; 1.1481x over previous
//
#include <hip/hip_runtime.h>

// LearnedSegmentEncoder on MI355X — independent-wave register-pipelined MFMA.
// B=8, C=128, P=65536, D=64, S=32.
// Identity: pooled = conv2_w @ mean_seg(relu(conv1_w@x+b1)) + b2 (conv2 hoisted
// past the segment mean), so only conv1 runs per-pixel: bf16 MFMA GEMM.
// Each wave owns 128 pixels (8 tiles of 16) and pipelines tile loads in
// registers (2 named buffers, one waitcnt per tile, no loop barriers).

#define B_ 8
#define C_ 128
#define P_ 65536
#define D_ 64
#define S_ 32
#define WPB 4            // waves per block
#define TMW 128          // pixels per wave
#define TMB (WPB * TMW)  // 512 pixels per block

typedef short  bf16x8 __attribute__((ext_vector_type(8)));
typedef float  f32x4  __attribute__((ext_vector_type(4)));

__device__ __forceinline__ short f2bf(float f) {
  union { float f; unsigned u; } v; v.f = f;
  unsigned r = v.u + 0x7fffu + ((v.u >> 16) & 1u);   // RNE
  return (short)(r >> 16);
}

__global__ __launch_bounds__(256) void w1_to_bf16(const float* __restrict__ w1,
                                                  short* __restrict__ wbf) {
  int i = blockIdx.x * 256 + threadIdx.x;
  if (i < C_ * D_) wbf[i] = f2bf(w1[i]);
}

// Grid (P/TMB, B) = (128, 8) = 1024 blocks -> exactly 4/CU, all resident.
__global__ __launch_bounds__(256, 4) void proj_mfma(
    const int* __restrict__ labels, const float* __restrict__ feat,
    const short* __restrict__ wbf, const float* __restrict__ b1,
    float* __restrict__ gsum, int* __restrict__ gcnt)
{
  // W1^T fragments, XOR-swizzled so 16 m-lanes hit 8 distinct 16B slots.
  __shared__ __align__(16) char wlds[D_ * 256];      // 16 KB: row d, 256 B/row
  __shared__ float s_acc[S_][68];
  __shared__ int   s_cnt[S_];

  const int tid  = threadIdx.x;
  const int wave = tid >> 6, l = tid & 63, m = l & 15, g = l >> 4;
  const int b    = blockIdx.y;
  const int px0  = blockIdx.x * TMB;

  // stage wbf -> swizzled LDS (32 elems = 4 x b128 per thread)
  #pragma unroll
  for (int i = 0; i < 4; ++i) {
    const int e = tid * 32 + i * 8;                  // 8192 bf16 total
    const int row = e >> 7, colB = (e & 127) * 2;
    *(bf16x8*)&wlds[row * 256 + (colB ^ ((row & 7) << 4))] =
        *(const bf16x8*)&wbf[e];
  }
  for (int i = tid; i < S_ * 68; i += 256) ((float*)s_acc)[i] = 0.f;
  if (tid < S_) s_cnt[tid] = 0;
  __syncthreads();

  const float* xpg = feat + (size_t)b * C_ * P_ + (size_t)(g * 8) * P_
                   + px0 + wave * TMW + m;
  const int*   lb  = labels + (size_t)b * P_ + px0 + wave * TMW;
  const int    xsw = (m & 7) << 4;

  float b1v[4];
  #pragma unroll
  for (int nt = 0; nt < 4; ++nt) b1v[nt] = b1[nt * 16 + m];

  float xvA[4][8], xvB[4][8];

#define ISSUE(dst, t_) do {                                                   \
    _Pragma("unroll") for (int kk = 0; kk < 4; ++kk)                          \
    _Pragma("unroll") for (int j = 0; j < 8; ++j)                             \
      dst[kk][j] = xpg[(size_t)(kk * 32 + j) * P_ + (t_) * 16];               \
  } while (0)

#define COMPUTE(src, t_) do {                                                 \
    f32x4 acc[4] = {{0,0,0,0},{0,0,0,0},{0,0,0,0},{0,0,0,0}};                 \
    _Pragma("unroll") for (int ks = 0; ks < 4; ++ks) {                        \
      bf16x8 af;                                                              \
      _Pragma("unroll") for (int j = 0; j < 8; ++j) af[j] = f2bf(src[ks][j]); \
      _Pragma("unroll") for (int nt = 0; nt < 4; ++nt) {                      \
        bf16x8 bwv = *(const bf16x8*)&wlds[(nt * 16 + m) * 256 +              \
                                           ((ks * 64 + g * 16) ^ xsw)];       \
        acc[nt] = __builtin_amdgcn_mfma_f32_16x16x32_bf16(af, bwv,            \
                                                          acc[nt], 0, 0, 0);  \
      }                                                                       \
    }                                                                         \
    const int4 lv = *(const int4*)&lb[(t_) * 16 + g * 4];                     \
    _Pragma("unroll") for (int nt = 0; nt < 4; ++nt)                          \
      _Pragma("unroll") for (int r = 0; r < 4; ++r) {                         \
        const int lab = ((r & 2) ? ((r & 1) ? lv.w : lv.z)                    \
                                 : ((r & 1) ? lv.y : lv.x)) & (S_ - 1);       \
        atomicAdd(&s_acc[lab][nt * 16 + m],                                   \
                  fmaxf(acc[nt][r] + b1v[nt], 0.f));                          \
      }                                                                       \
    if (m < 4) {                                                              \
      const int lab = ((m & 2) ? ((m & 1) ? lv.w : lv.z)                      \
                               : ((m & 1) ? lv.y : lv.x)) & (S_ - 1);         \
      atomicAdd(&s_cnt[lab], 1);                                              \
    }                                                                         \
  } while (0)

  ISSUE(xvA, 0);
  __builtin_amdgcn_sched_barrier(0);
  #pragma unroll
  for (int t = 0; t < 8; t += 2) {
    ISSUE(xvB, t + 1);
    __builtin_amdgcn_sched_barrier(0);
    COMPUTE(xvA, t);
    __builtin_amdgcn_sched_barrier(0);
    if (t + 2 < 8) {
      ISSUE(xvA, t + 2);
      __builtin_amdgcn_sched_barrier(0);
    }
    COMPUTE(xvB, t + 1);
    __builtin_amdgcn_sched_barrier(0);
  }
#undef ISSUE
#undef COMPUTE

  __syncthreads();
  for (int i = tid; i < S_ * D_; i += 256)
    atomicAdd(&gsum[(size_t)b * S_ * D_ + i], s_acc[i >> 6][i & 63]);
  if (tid < S_) atomicAdd(&gcnt[b * S_ + tid], s_cnt[tid]);
}

// Grid (S, B), 64 lanes: all (b,s) blocks independent; ballot-based rank.
__global__ __launch_bounds__(64) void seg_finalize2(
    const float* __restrict__ gsum, const int* __restrict__ gcnt,
    const float* __restrict__ w2, const float* __restrict__ b2,
    const float* __restrict__ emb, const float* __restrict__ wo,
    const float* __restrict__ bo, float* __restrict__ out)
{
  const int s = blockIdx.x, b = blockIdx.y, o = threadIdx.x;
  const int co = (o < S_) ? gcnt[b * S_ + o] : 0;
  const unsigned long long mask = __ballot(co > 0);
  const int cnt = gcnt[b * S_ + s];
  if (cnt <= 0) return;                               // uniform exit
  const int rank = __popcll(mask & ((1ull << s) - 1ull));

  __shared__ float s_mean[D_], s_pool[D_];
  s_mean[o] = gsum[((size_t)b * S_ + s) * D_ + o] * (1.f / (float)cnt);
  __syncthreads();
  float pooled = b2[o];
  #pragma unroll
  for (int d = 0; d < D_; ++d) pooled += w2[o * D_ + d] * s_mean[d];
  s_pool[o] = pooled;
  __syncthreads();
  float r = bo[o];
  #pragma unroll
  for (int e = 0; e < D_; ++e) r += wo[o * 2 * D_ + e] * s_pool[e];
  #pragma unroll
  for (int e = 0; e < D_; ++e) r += wo[o * 2 * D_ + D_ + e] * emb[s * D_ + e];
  out[((size_t)b * S_ + rank) * D_ + o] = r;
}

extern "C" void kernel_launch(void* const* d_in, const int* in_sizes, int n_in,
                              void* d_out, int out_size, void* d_ws, size_t ws_size,
                              hipStream_t stream) {
  const int*   labels = (const int*)  d_in[0];
  const float* feat   = (const float*)d_in[1];
  const float* w1     = (const float*)d_in[2];
  const float* b1     = (const float*)d_in[3];
  const float* w2     = (const float*)d_in[4];
  const float* b2     = (const float*)d_in[5];
  const float* emb    = (const float*)d_in[6];
  const float* wo     = (const float*)d_in[7];
  const float* bo     = (const float*)d_in[8];
  float* out = (float*)d_out;

  // ws layout: gsum | gcnt | wbf
  char* w = (char*)d_ws;
  float* gsum = (float*)w;   w += (size_t)B_ * S_ * D_ * 4;
  int*   gcnt = (int*)w;     w += (size_t)B_ * S_ * 4;
  short* wbf  = (short*)w;

  hipMemsetAsync(d_ws, 0, (size_t)B_ * S_ * D_ * 4 + (size_t)B_ * S_ * 4, stream);
  hipMemsetAsync(d_out, 0, (size_t)out_size * sizeof(float), stream);

  w1_to_bf16<<<(C_ * D_ + 255) / 256, 256, 0, stream>>>(w1, wbf);

  dim3 grid(P_ / TMB, B_);
  proj_mfma<<<grid, 256, 0, stream>>>(labels, feat, wbf, b1, gsum, gcnt);
  seg_finalize2<<<dim3(S_, B_), 64, 0, stream>>>(gsum, gcnt, w2, b2, emb, wo, bo, out);
}